// Round 3
// baseline (418.841 us; speedup 1.0000x reference)
//
#include <hip/hip_runtime.h>
#include <hip/hip_bf16.h>

typedef unsigned short ushort_t;
typedef unsigned int uint_t;
typedef __attribute__((ext_vector_type(4))) float f32x4;
typedef __attribute__((ext_vector_type(8))) short bf16x8;

#define B_DIM 512
#define IN_DIM 4096
#define OUT_DIM 4096
#define BN 64          // output cols per block
#define BK 32
#define KSPLIT 8       // kseg = 512, 16 k-steps per block

// ---------- helpers ----------
__device__ __forceinline__ ushort_t f2bf(float f) {
    union { float f; uint_t u; } v; v.f = f;
    uint_t r = v.u + 0x7fffu + ((v.u >> 16) & 1u);   // round-to-nearest-even
    return (ushort_t)(r >> 16);
}

__device__ __forceinline__ void async_copy16(void* lds, const void* g) {
    __builtin_amdgcn_global_load_lds(
        (const __attribute__((address_space(1))) uint_t*)g,
        (__attribute__((address_space(3))) uint_t*)lds, 16, 0, 0);
}

// ---------- kernel 1: x -> bf16 ----------
__global__ __launch_bounds__(256) void conv_x(const float4* __restrict__ X4,
                                              ushort_t* __restrict__ Xb) {
    size_t i = (size_t)blockIdx.x * 256 + threadIdx.x;   // one float4 per thread
    float4 a = X4[i];
    ushort_t r[4] = { f2bf(a.x), f2bf(a.y), f2bf(a.z), f2bf(a.w) };
    *(uint2*)(Xb + i * 4) = *(const uint2*)r;            // 8B/lane coalesced
}

// ---------- kernel 2: fused dequant + GEMM ----------
// Block (n0, kz): computes partial[kz][0:512][n0:n0+64] over k-seg of 512.
// BM = 512 = full M, so U is streamed from HBM exactly once across the grid
// (no materialized W). U-tile dequantized in-register to bf16 LDS; X-tile
// staged via global_load_lds width=16.
__global__ __launch_bounds__(256, 2) void gemm_fused(
    const ushort_t* __restrict__ Xb,  // M x K bf16
    const float4* __restrict__ U4,    // (OUT*IN) float4 rows
    const float* __restrict__ q,
    const int* __restrict__ expo,
    float* __restrict__ part)         // KSPLIT x M x N fp32
{
    const int K = IN_DIM, N = OUT_DIM, M = B_DIM;
    __shared__ ushort_t sX[512 * 32];  // 32 KB
    __shared__ ushort_t sU[64 * 32];   // 4 KB

    const int tid  = threadIdx.x;
    const int lane = tid & 63;
    const int wave = tid >> 6;
    const int n0 = blockIdx.x * BN;
    const int kz = blockIdx.y;
    const int kseg = K / KSPLIT;                        // 512
    const size_t kbase = (size_t)kz * kseg;

    const float scale = exp2f((float)expo[0]) * (1.0f / 7.0f);
    const float t0 = q[0] * scale, t1 = q[1] * scale,
                t2 = q[2] * scale, t3 = q[3] * scale;

    // X staging: 8 passes x 64 rows; thread t -> row p*64+(t>>2), col (t&3)*8
    const int xrow = tid >> 2;
    const int xcol = (tid & 3) * 8;
    const ushort_t* gx = Xb + (size_t)xrow * K + kbase + xcol;
    ushort_t* lx = sX + tid * 8;   // wave-uniform base + lane*16B

    // U dequant staging: thread t -> n rows {t>>4 + r*16}, k pair 2*(t&15)
    // lanes with same n read 512B contiguous (32B/lane) — coalesced.
    const int nb = tid >> 4;
    const int kp = tid & 15;
    const float4* gu = U4 + (size_t)(n0 + nb) * K + kbase + 2 * kp;
    uint_t* lu = (uint_t*)sU + nb * 16 + kp;   // 2-way bank alias = free

    // fragment addressing (16x16x32 bf16, verified layout m89/m91)
    const int quad = lane >> 4;
    const int r16  = lane & 15;
    const ushort_t* fa = sX + (wave * 128 + r16) * 32 + quad * 8;
    const ushort_t* fb = sU + r16 * 32 + quad * 8;

    f32x4 acc[8][4] = {};

    const int nsteps = kseg / BK;                       // 16
    for (int s = 0; s < nsteps; ++s) {
#pragma unroll
        for (int p = 0; p < 8; ++p)
            async_copy16(lx + p * 2048, gx + (size_t)p * 64 * K);
        gx += BK;
#pragma unroll
        for (int r = 0; r < 4; ++r) {
            const float4* g = gu + (size_t)r * 16 * K;
            float4 ua = g[0], ub = g[1];
            float w0 = ua.x * t0 + ua.y * t1 + ua.z * t2 + ua.w * t3;
            float w1 = ub.x * t0 + ub.y * t1 + ub.z * t2 + ub.w * t3;
            lu[r * 256] = (uint_t)f2bf(w0) | ((uint_t)f2bf(w1) << 16);
        }
        gu += BK;
        __syncthreads();

        bf16x8 bv[4];
#pragma unroll
        for (int j = 0; j < 4; ++j)
            bv[j] = *(const bf16x8*)(fb + j * 16 * 32);
#pragma unroll
        for (int i = 0; i < 8; ++i) {
            bf16x8 av = *(const bf16x8*)(fa + i * 16 * 32);
#pragma unroll
            for (int j = 0; j < 4; ++j)
                acc[i][j] = __builtin_amdgcn_mfma_f32_16x16x32_bf16(
                    av, bv[j], acc[i][j], 0, 0, 0);
        }
        __syncthreads();
    }

    // epilogue: C/D layout col=lane&15, row=quad*4+reg
    float* outp = part + (size_t)kz * M * N;
#pragma unroll
    for (int i = 0; i < 8; ++i) {
        const int mrow = wave * 128 + i * 16 + quad * 4;
#pragma unroll
        for (int j = 0; j < 4; ++j) {
            const int ncol = n0 + j * 16 + r16;
            float* o = outp + (size_t)mrow * N + ncol;
#pragma unroll
            for (int r = 0; r < 4; ++r)
                o[(size_t)r * N] = acc[i][j][r];
        }
    }
}

// ---------- kernel 3: out = sum_k part[k] + bias ----------
__global__ __launch_bounds__(256) void reduce_bias(const float4* __restrict__ part,
                                                   const float4* __restrict__ bias,
                                                   float4* __restrict__ out) {
    const int MN4 = (B_DIM * OUT_DIM) / 4;   // 524288
    int i = blockIdx.x * 256 + threadIdx.x;
    float4 bb = bias[i & 1023];              // OUT/4 = 1024
    float sx = bb.x, sy = bb.y, sz = bb.z, sw = bb.w;
#pragma unroll
    for (int k = 0; k < KSPLIT; ++k) {
        float4 p = part[i + (size_t)k * MN4];
        sx += p.x; sy += p.y; sz += p.z; sw += p.w;
    }
    float4 o; o.x = sx; o.y = sy; o.z = sz; o.w = sw;
    out[i] = o;
}

extern "C" void kernel_launch(void* const* d_in, const int* in_sizes, int n_in,
                              void* d_out, int out_size, void* d_ws, size_t ws_size,
                              hipStream_t stream) {
    const float* x    = (const float*)d_in[0];   // (512, 4096)
    const float* U    = (const float*)d_in[1];   // (4096*4096, 4)
    const float* q    = (const float*)d_in[2];   // (4,)
    const float* b    = (const float*)d_in[3];   // (4096,)
    const int*   expo = (const int*)d_in[4];     // scalar
    float* out = (float*)d_out;

    char* ws = (char*)d_ws;
    float*    prt = (float*)ws;                          // 64 MB fp32 partials
    ushort_t* Xb  = (ushort_t*)(ws + 67108864);          // 4 MB bf16 (B, IN)

    // x conversion: 2.09M elems / 4 = 524288 threads
    conv_x<<<2048, 256, 0, stream>>>((const float4*)x, Xb);
    // fused dequant+GEMM: grid (N/BN=64, KSPLIT=8) = 512 blocks, 2/CU
    gemm_fused<<<dim3(64, KSPLIT), 256, 0, stream>>>(Xb, (const float4*)U,
                                                     q, expo, prt);
    // reduce: 2.09M elems / 4 = 524288 threads
    reduce_bias<<<2048, 256, 0, stream>>>((const float4*)prt, (const float4*)b,
                                          (float4*)out);
}

// Round 4
// 415.556 us; speedup vs baseline: 1.0079x; 1.0079x over previous
//
#include <hip/hip_runtime.h>
#include <hip/hip_bf16.h>

typedef unsigned short ushort_t;
typedef unsigned int uint_t;
typedef __attribute__((ext_vector_type(4))) float f32x4;
typedef __attribute__((ext_vector_type(8))) short bf16x8;

#define B_DIM 512
#define IN_DIM 4096
#define OUT_DIM 4096
#define BN 128         // output cols per block
#define BK 32
#define KSPLIT 8       // kseg = 512, 16 k-steps per block

// ---------- helpers ----------
__device__ __forceinline__ ushort_t f2bf(float f) {
    union { float f; uint_t u; } v; v.f = f;
    uint_t r = v.u + 0x7fffu + ((v.u >> 16) & 1u);   // round-to-nearest-even
    return (ushort_t)(r >> 16);
}

__device__ __forceinline__ void async_copy16(void* lds, const void* g) {
    __builtin_amdgcn_global_load_lds(
        (const __attribute__((address_space(1))) uint_t*)g,
        (__attribute__((address_space(3))) uint_t*)lds, 16, 0, 0);
}

// ---------- kernel 1: x -> bf16 ----------
__global__ __launch_bounds__(256) void conv_x(const float4* __restrict__ X4,
                                              ushort_t* __restrict__ Xb) {
    size_t i = (size_t)blockIdx.x * 256 + threadIdx.x;   // one float4 per thread
    float4 a = X4[i];
    ushort_t r[4] = { f2bf(a.x), f2bf(a.y), f2bf(a.z), f2bf(a.w) };
    *(uint2*)(Xb + i * 4) = *(const uint2*)r;            // 8B/lane coalesced
}

// ---------- kernel 2: fused dequant + GEMM, bf16 partials ----------
// Block (n0, kz): partial[kz][0:512][n0:n0+128] over one k-seg of 512.
// BM = 512 = full M -> U streamed from HBM exactly once across the grid.
// 512 threads = 8 waves: wave (r,c) with r=wave&3 (128-row strip),
// c=wave>>2 (64-col half). 32 MFMA per wave per barrier.
__global__ __launch_bounds__(512, 2) void gemm_fused(
    const ushort_t* __restrict__ Xb,  // M x K bf16
    const float4* __restrict__ U4,    // (OUT*IN) float4 rows
    const float* __restrict__ q,
    const int* __restrict__ expo,
    ushort_t* __restrict__ part)      // KSPLIT x M x N bf16
{
    const int K = IN_DIM, N = OUT_DIM, M = B_DIM;
    __shared__ ushort_t sX[512 * 32];  // 32 KB
    __shared__ ushort_t sU[128 * 32];  // 8 KB

    const int tid  = threadIdx.x;
    const int lane = tid & 63;
    const int wave = tid >> 6;
    const int wrow = (wave & 3) * 128;
    const int wcol = (wave >> 2) * 64;
    const int n0 = blockIdx.x * BN;
    const int kz = blockIdx.y;
    const int kseg = K / KSPLIT;                        // 512
    const size_t kbase = (size_t)kz * kseg;

    const float scale = exp2f((float)expo[0]) * (1.0f / 7.0f);
    const float t0 = q[0] * scale, t1 = q[1] * scale,
                t2 = q[2] * scale, t3 = q[3] * scale;

    // X staging: 4 passes x 128 rows; thread t -> row p*128+(t>>2), col (t&3)*8
    const int xrow = tid >> 2;                 // 0..127
    const int xcol = (tid & 3) * 8;
    const ushort_t* gx = Xb + (size_t)xrow * K + kbase + xcol;
    ushort_t* lx = sX + tid * 8;   // wave-uniform base + lane*16B per pass

    // U dequant staging: thread t -> rows {t>>4 + r*32}, k-pair 2*(t&15)
    // 16 threads x 32B = 512B contiguous per row — coalesced.
    const int nb = tid >> 4;                   // 0..31
    const int kp = tid & 15;
    const float4* gu = U4 + (size_t)(n0 + nb) * K + kbase + 2 * kp;
    uint_t* lu = (uint_t*)sU + nb * 16 + kp;

    // fragment addressing (16x16x32 bf16, C/D layout verified m89/m91)
    const int quad = lane >> 4;
    const int r16  = lane & 15;
    const ushort_t* fa = sX + (wrow + r16) * 32 + quad * 8;
    const ushort_t* fb = sU + (wcol + r16) * 32 + quad * 8;

    f32x4 acc[8][4] = {};   // 128 VGPRs

    const int nsteps = kseg / BK;                       // 16
    for (int s = 0; s < nsteps; ++s) {
#pragma unroll
        for (int p = 0; p < 4; ++p)
            async_copy16(lx + p * 4096, gx + (size_t)p * 128 * K);
        gx += BK;
#pragma unroll
        for (int r = 0; r < 4; ++r) {
            const float4* g = gu + (size_t)r * 32 * K;
            float4 ua = g[0], ub = g[1];
            float w0 = ua.x * t0 + ua.y * t1 + ua.z * t2 + ua.w * t3;
            float w1 = ub.x * t0 + ub.y * t1 + ub.z * t2 + ub.w * t3;
            lu[r * 512] = (uint_t)f2bf(w0) | ((uint_t)f2bf(w1) << 16);
        }
        gu += BK;
        __syncthreads();

        bf16x8 bv[4];
#pragma unroll
        for (int j = 0; j < 4; ++j)
            bv[j] = *(const bf16x8*)(fb + j * 16 * 32);
#pragma unroll
        for (int i = 0; i < 8; ++i) {
            bf16x8 av = *(const bf16x8*)(fa + i * 16 * 32);
#pragma unroll
            for (int j = 0; j < 4; ++j)
                acc[i][j] = __builtin_amdgcn_mfma_f32_16x16x32_bf16(
                    av, bv[j], acc[i][j], 0, 0, 0);
        }
        __syncthreads();
    }

    // epilogue: C/D layout col=lane&15, row=quad*4+reg; store bf16 partials
    ushort_t* outp = part + (size_t)kz * M * N;
#pragma unroll
    for (int i = 0; i < 8; ++i) {
        const int mrow = wrow + i * 16 + quad * 4;
#pragma unroll
        for (int j = 0; j < 4; ++j) {
            const int ncol = n0 + wcol + j * 16 + r16;
            ushort_t* o = outp + (size_t)mrow * N + ncol;
#pragma unroll
            for (int r = 0; r < 4; ++r)
                o[(size_t)r * N] = f2bf(acc[i][j][r]);
        }
    }
}

// ---------- kernel 3: out = sum_k bf16-part[k] + bias ----------
__global__ __launch_bounds__(256) void reduce_bias(const uint2* __restrict__ partb,
                                                   const float4* __restrict__ bias,
                                                   float4* __restrict__ out) {
    const int MN4 = (B_DIM * OUT_DIM) / 4;   // 524288 groups of 4 bf16
    int i = blockIdx.x * 256 + threadIdx.x;
    float4 bb = bias[i & 1023];              // OUT/4 = 1024
    float sx = bb.x, sy = bb.y, sz = bb.z, sw = bb.w;
#pragma unroll
    for (int k = 0; k < KSPLIT; ++k) {
        uint2 p = partb[i + (size_t)k * MN4];    // 4 bf16
        sx += __uint_as_float(p.x << 16);
        sy += __uint_as_float(p.x & 0xffff0000u);
        sz += __uint_as_float(p.y << 16);
        sw += __uint_as_float(p.y & 0xffff0000u);
    }
    float4 o; o.x = sx; o.y = sy; o.z = sz; o.w = sw;
    out[i] = o;
}

extern "C" void kernel_launch(void* const* d_in, const int* in_sizes, int n_in,
                              void* d_out, int out_size, void* d_ws, size_t ws_size,
                              hipStream_t stream) {
    const float* x    = (const float*)d_in[0];   // (512, 4096)
    const float* U    = (const float*)d_in[1];   // (4096*4096, 4)
    const float* q    = (const float*)d_in[2];   // (4,)
    const float* b    = (const float*)d_in[3];   // (4096,)
    const int*   expo = (const int*)d_in[4];     // scalar
    float* out = (float*)d_out;

    char* ws = (char*)d_ws;
    ushort_t* prtb = (ushort_t*)ws;                      // 32 MB bf16 partials
    ushort_t* Xb   = (ushort_t*)(ws + 33554432);         // 4 MB bf16 (B, IN)

    // x conversion: 2.09M elems / 4 = 524288 threads
    conv_x<<<2048, 256, 0, stream>>>((const float4*)x, Xb);
    // fused dequant+GEMM: grid (N/BN=32, KSPLIT=8) = 256 blocks, 512 thr
    gemm_fused<<<dim3(32, KSPLIT), 512, 0, stream>>>(Xb, (const float4*)U,
                                                     q, expo, prtb);
    // reduce: 2.09M outputs / 4 = 524288 threads
    reduce_bias<<<2048, 256, 0, stream>>>((const uint2*)prtb, (const float4*)b,
                                          (float4*)out);
}